// Round 3
// baseline (164.876 us; speedup 1.0000x reference)
//
#include <hip/hip_runtime.h>

// HierarchicalSoftmax: out[b] = prod_l sigmoid(+/- (W[node_l]·emb[b] + bias[node_l]))
// One wave per sample; D=512 -> 8 floats/lane (2x float4) in registers.
//
// R2 changes vs R1:
//  - Unroll 8 (was 4): 16 independent 16B row-loads in flight per group,
//    8 interleaved shfl-reduce chains (cross-lane latency fully hidden).
//  - Trip count padded to a multiple of 8 with dummy node-0 steps whose
//    factors are masked to 1.0 -> NO serial remainder loop (the R1 remainder
//    was up to 3 fully-serialized steps ~ 40% of critical path for plen~23).
//    Padding reads row 0 / bias[0], which is L2-resident-hot => nearly free.
//  - Metadata still preloaded lane-parallel; trip count from ballot+ffs of
//    node==0 (first root hit == path length; padding rows are all-0).

#define HS_D 512

__device__ __forceinline__ float dot8(const float4 e0, const float4 e1,
                                      const float4 a, const float4 b) {
    float p;
    p = e0.x * a.x;
    p = fmaf(e0.y, a.y, p);
    p = fmaf(e0.z, a.z, p);
    p = fmaf(e0.w, a.w, p);
    p = fmaf(e1.x, b.x, p);
    p = fmaf(e1.y, b.y, p);
    p = fmaf(e1.z, b.z, p);
    p = fmaf(e1.w, b.w, p);
    return p;
}

__device__ __forceinline__ float fast_sigmoid(float s) {
    return __builtin_amdgcn_rcpf(1.0f + __expf(-s));
}

__global__ __launch_bounds__(256) void hs_kernel(
    const float* __restrict__ emb,     // [B, 512]
    const float* __restrict__ W,       // [V-1, 512]
    const float* __restrict__ bias,    // [V-1]
    const int*   __restrict__ target,  // [B]
    const int*   __restrict__ nodes,   // [V, L]
    const int*   __restrict__ dirs,    // [V, L]
    float*       __restrict__ out,     // [B]
    int B, int L)
{
    const int wid  = blockIdx.x * (blockDim.x >> 6) + (threadIdx.x >> 6);
    const int lane = threadIdx.x & 63;
    if (wid >= B) return;

    const float4* e4 = (const float4*)(emb + (size_t)wid * HS_D);
    const float4 e0 = e4[lane];
    const float4 e1 = e4[lane + 64];

    const int t = __builtin_amdgcn_readfirstlane(target[wid]);

    // Lane-parallel metadata preload (L ~ 27 < 64). Lanes >= L hold 0,
    // which aliases the "padding step" (node 0, masked out) semantics.
    int nval = 0, dval = 0;
    if (lane < L) {
        nval = nodes[(size_t)t * L + lane];
        dval = dirs [(size_t)t * L + lane];
    }
    const unsigned long long rootmask = __ballot(lane < L && nval == 0);
    const int plen = __ffsll((long long)rootmask);      // 1-based: steps 0..plen-1 real
    const unsigned long long dirmask = __ballot(dval != 0);

    const int plen8 = (plen + 7) & ~7;                  // padded trip count (<= 64)

    float prod = 1.0f;

    for (int l = 0; l < plen8; l += 8) {
        int   n[8];
        float4 a[8], b[8];

        #pragma unroll
        for (int j = 0; j < 8; ++j)
            n[j] = __builtin_amdgcn_readfirstlane(__shfl(nval, l + j, 64));

        #pragma unroll
        for (int j = 0; j < 8; ++j) {
            const float4* w = (const float4*)(W + (size_t)n[j] * HS_D);
            a[j] = w[lane];
            b[j] = w[lane + 64];
        }

        float p[8];
        #pragma unroll
        for (int j = 0; j < 8; ++j) p[j] = dot8(e0, e1, a[j], b[j]);

        // 8 interleaved butterfly chains — DS-throughput-bound, latency hidden
        #pragma unroll
        for (int m = 32; m > 0; m >>= 1) {
            #pragma unroll
            for (int j = 0; j < 8; ++j) p[j] += __shfl_xor(p[j], m, 64);
        }

        #pragma unroll
        for (int j = 0; j < 8; ++j) {
            float s = p[j] + bias[n[j]];
            s = ((dirmask >> (l + j)) & 1ull) ? s : -s;
            const float f = (l + j < plen) ? fast_sigmoid(s) : 1.0f;
            prod *= f;
        }
    }

    if (lane == 0) out[wid] = prod;
}

extern "C" void kernel_launch(void* const* d_in, const int* in_sizes, int n_in,
                              void* d_out, int out_size, void* d_ws, size_t ws_size,
                              hipStream_t stream)
{
    const float* emb    = (const float*)d_in[0];
    const float* W      = (const float*)d_in[1];
    const float* bias   = (const float*)d_in[2];
    const int*   target = (const int*)  d_in[3];
    const int*   nodes  = (const int*)  d_in[4];
    const int*   dirs   = (const int*)  d_in[5];
    float*       out    = (float*)d_out;

    const int B = in_sizes[3];              // 4096
    const int V = in_sizes[2] + 1;          // bias has V-1 entries
    const int L = in_sizes[4] / V;          // padded max path length (~27)

    const int wavesPerBlock = 4;            // 256 threads
    const int grid = (B + wavesPerBlock - 1) / wavesPerBlock;
    hs_kernel<<<grid, 256, 0, stream>>>(emb, W, bias, target, nodes, dirs, out, B, L);
}